// Round 6
// baseline (116.922 us; speedup 1.0000x reference)
//
#include <hip/hip_runtime.h>
#include <cstdint>
#include <cstddef>

#define DIMX  1024
#define NH    8
#define HD    64
#define QKD   512            // NH*HD
#define VDD   128            // DIMX/NH
#define BATCH 4
#define SEQ   1024
#define NPOS  (BATCH*SEQ)    // 4096
#define TW    (2*QKD + DIMX) // 2048
#define SCALE 0.125f         // HD^-0.5 (folded into Qb at pack time)

typedef __bf16 bf16x8 __attribute__((ext_vector_type(8)));
typedef float  f32x4  __attribute__((ext_vector_type(4)));
typedef float  f32x16 __attribute__((ext_vector_type(16)));

__device__ __forceinline__ ushort f2bf(float f) {
    unsigned b = __float_as_uint(f);
    return (ushort)((b + 0x7FFFu + ((b >> 16) & 1u)) >> 16);   // RNE, finite data
}

__device__ __forceinline__ unsigned cvtpk(float lo, float hi) {
    unsigned r;
    asm("v_cvt_pk_bf16_f32 %0, %1, %2" : "=v"(r) : "v"(lo), "v"(hi));
    return r;
}

// v_permlane32_swap_b32: a' = [a.lo | b.lo(from lane-32)], b' = [a.hi | b.hi]
__device__ __forceinline__ void plswap(unsigned &a, unsigned &b) {
    asm("v_permlane32_swap_b32 %0, %1" : "+v"(a), "+v"(b));
}

#define GLD16(src, dst) __builtin_amdgcn_global_load_lds(                      \
    (const __attribute__((address_space(1))) unsigned int*)(src),              \
    (__attribute__((address_space(3))) unsigned int*)(dst), 16, 0, 0)

// swizzled LDS element index for [row][col] tiles with 64-elem (128B) rows
#define SW(row, col) ((row)*64 + ((col) ^ (((row)&7)<<3)))

// XCD-aware block swizzle (bijective: nwg % 8 == 0 for all our grids)
__device__ __forceinline__ int2 xcd_swz(int gx, int gy) {
    const int nwg = gx * gy;
    int id = blockIdx.y * gx + blockIdx.x;
    id = (id & 7) * (nwg >> 3) + (id >> 3);
    return make_int2(id % gx, id / gx);
}

// ---------------------------------------------------------------------------
// fp32 -> bf16 cast (same layout). n4 = elem_count/4.
// ---------------------------------------------------------------------------
__global__ __launch_bounds__(256)
void cast_bf16(const float* __restrict__ in, ushort* __restrict__ out, int n4)
{
    const int i = blockIdx.x * 256 + threadIdx.x;
    if (i >= n4) return;
    float4 v = *(const float4*)(in + (size_t)i * 4);
    ushort4 o;
    o.x = f2bf(v.x); o.y = f2bf(v.y); o.z = f2bf(v.z); o.w = f2bf(v.w);
    *(ushort4*)(out + (size_t)i * 4) = o;
}

// ---------------------------------------------------------------------------
// W[K][N] fp32 -> WT[N][K] bf16 (transpose + cast). 32x32 tiles.
// ---------------------------------------------------------------------------
__global__ __launch_bounds__(256)
void transpose_cast(const float* __restrict__ W, ushort* __restrict__ WT,
                    int K, int N)
{
    __shared__ float tile[32][33];
    const int bn = blockIdx.x * 32;
    const int bk = blockIdx.y * 32;
    const int tx = threadIdx.x & 31;
    const int ty = threadIdx.x >> 5;
    #pragma unroll
    for (int i = ty; i < 32; i += 8)
        tile[i][tx] = W[(size_t)(bk + i) * N + bn + tx];
    __syncthreads();
    #pragma unroll
    for (int i = ty; i < 32; i += 8)
        WT[(size_t)(bn + i) * K + bk + tx] = f2bf(tile[tx][i]);
}

// ---------------------------------------------------------------------------
// GEMM1 with split epilogue: cols [0,1024) -> t1 fp32 (q,k);
// cols [1024,2048) -> transposed bf16 Vt[bh][vd][S].
// ---------------------------------------------------------------------------
__global__ __launch_bounds__(256, 2)
void gemm_qkv(const ushort* __restrict__ A, const ushort* __restrict__ BT,
              float* __restrict__ t1, ushort* __restrict__ Vt)
{
    const int K = DIMX, N = TW;
    __shared__ __align__(16) ushort lA[128 * 32];
    __shared__ __align__(16) ushort lB[128 * 32];

    const int2 bij = xcd_swz(N/128, NPOS/128);
    const int tid  = threadIdx.x;
    const int lane = tid & 63;
    const int wave = tid >> 6;
    const int wr   = wave >> 1;
    const int wc   = wave & 1;
    const int bm   = bij.y * 128;
    const int bn   = bij.x * 128;

    const int r0 = wave * 32 + (lane >> 2);
    const int kc = (lane & 3) * 8;
    const ushort* a0 = A  + (size_t)(bm + r0) * K + kc;
    const ushort* a1 = A  + (size_t)(bm + r0 + 16) * K + kc;
    const ushort* b0 = BT + (size_t)(bn + r0) * K + kc;
    const ushort* b1 = BT + (size_t)(bn + r0 + 16) * K + kc;
    ushort* lA0 = lA + wave * 1024;
    ushort* lA1 = lA0 + 512;
    ushort* lB0 = lB + wave * 1024;
    ushort* lB1 = lB0 + 512;

    const int fr = lane & 15;
    const int kh = (lane >> 4) * 8;
    const ushort* ra = lA + (wr * 64 + fr) * 32 + kh;
    const ushort* rb = lB + (wc * 64 + fr) * 32 + kh;

    f32x4 acc[4][4] = {};

    for (int k0 = 0; k0 < K; k0 += 32) {
        GLD16(a0 + k0, lA0);
        GLD16(a1 + k0, lA1);
        GLD16(b0 + k0, lB0);
        GLD16(b1 + k0, lB1);
        asm volatile("s_waitcnt vmcnt(0)" ::: "memory");
        __syncthreads();
        bf16x8 af[4], bfr[4];
        #pragma unroll
        for (int m = 0; m < 4; ++m) af[m]  = *(const bf16x8*)(ra + m * 512);
        #pragma unroll
        for (int n = 0; n < 4; ++n) bfr[n] = *(const bf16x8*)(rb + n * 512);
        #pragma unroll
        for (int m = 0; m < 4; ++m)
            #pragma unroll
            for (int n = 0; n < 4; ++n)
                acc[m][n] = __builtin_amdgcn_mfma_f32_16x16x32_bf16(
                    af[m], bfr[n], acc[m][n], 0, 0, 0);
        __syncthreads();
    }

    const int orow = (lane >> 4) * 4;
    if (bn < 1024) {
        #pragma unroll
        for (int m = 0; m < 4; ++m)
            #pragma unroll
            for (int n = 0; n < 4; ++n) {
                float* dst = t1 + (size_t)(bm + wr * 64 + m * 16 + orow) * 1024
                               + bn + wc * 64 + n * 16 + fr;
                #pragma unroll
                for (int q = 0; q < 4; ++q)
                    dst[(size_t)q * 1024] = acc[m][n][q];
            }
    } else {
        #pragma unroll
        for (int m = 0; m < 4; ++m)
            #pragma unroll
            for (int n = 0; n < 4; ++n) {
                const int row0 = bm + wr * 64 + m * 16 + orow;   // 4-aligned
                const int cv   = bn + wc * 64 + n * 16 + fr - 1024;
                const int hh = cv >> 7, vd = cv & 127;
                const int bb = row0 >> 10, ss = row0 & 1023;
                ushort o4[4];
                #pragma unroll
                for (int q = 0; q < 4; ++q) o4[q] = f2bf(acc[m][n][q]);
                *(ushort4*)&Vt[((size_t)(bb*NH + hh)*VDD + vd)*SEQ + ss] =
                    *(ushort4*)o4;
            }
    }
}

// ---------------------------------------------------------------------------
// GEMM2: C[M][N] fp32 = A[M][K] * BT[N][K]^T (both bf16). + XCD swizzle.
// ---------------------------------------------------------------------------
__global__ __launch_bounds__(256, 2)
void gemm_bf16_mfma(const ushort* __restrict__ A, const ushort* __restrict__ BT,
                    float* __restrict__ C, int M, int N, int K)
{
    __shared__ __align__(16) ushort lA[128 * 32];
    __shared__ __align__(16) ushort lB[128 * 32];

    const int2 bij = xcd_swz(N/128, M/128);
    const int tid  = threadIdx.x;
    const int lane = tid & 63;
    const int wave = tid >> 6;
    const int wr   = wave >> 1;
    const int wc   = wave & 1;
    const int bm   = bij.y * 128;
    const int bn   = bij.x * 128;

    const int r0 = wave * 32 + (lane >> 2);
    const int kc = (lane & 3) * 8;
    const ushort* a0 = A  + (size_t)(bm + r0) * K + kc;
    const ushort* a1 = A  + (size_t)(bm + r0 + 16) * K + kc;
    const ushort* b0 = BT + (size_t)(bn + r0) * K + kc;
    const ushort* b1 = BT + (size_t)(bn + r0 + 16) * K + kc;
    ushort* lA0 = lA + wave * 1024;
    ushort* lA1 = lA0 + 512;
    ushort* lB0 = lB + wave * 1024;
    ushort* lB1 = lB0 + 512;

    const int fr = lane & 15;
    const int kh = (lane >> 4) * 8;
    const ushort* ra = lA + (wr * 64 + fr) * 32 + kh;
    const ushort* rb = lB + (wc * 64 + fr) * 32 + kh;

    f32x4 acc[4][4] = {};

    for (int k0 = 0; k0 < K; k0 += 32) {
        GLD16(a0 + k0, lA0);
        GLD16(a1 + k0, lA1);
        GLD16(b0 + k0, lB0);
        GLD16(b1 + k0, lB1);
        asm volatile("s_waitcnt vmcnt(0)" ::: "memory");
        __syncthreads();
        bf16x8 af[4], bfr[4];
        #pragma unroll
        for (int m = 0; m < 4; ++m) af[m]  = *(const bf16x8*)(ra + m * 512);
        #pragma unroll
        for (int n = 0; n < 4; ++n) bfr[n] = *(const bf16x8*)(rb + n * 512);
        #pragma unroll
        for (int m = 0; m < 4; ++m)
            #pragma unroll
            for (int n = 0; n < 4; ++n)
                acc[m][n] = __builtin_amdgcn_mfma_f32_16x16x32_bf16(
                    af[m], bfr[n], acc[m][n], 0, 0, 0);
        __syncthreads();
    }

    const int orow = (lane >> 4) * 4;
    #pragma unroll
    for (int m = 0; m < 4; ++m)
        #pragma unroll
        for (int n = 0; n < 4; ++n) {
            float* dst = C + (size_t)(bm + wr * 64 + m * 16 + orow) * N
                           + bn + wc * 64 + n * 16 + fr;
            #pragma unroll
            for (int q = 0; q < 4; ++q)
                dst[(size_t)q * N] = acc[m][n][q];
        }
}

// ---------------------------------------------------------------------------
// Fused masked rotation + bf16 pack (SCALE folded into Qb).
// ---------------------------------------------------------------------------
__global__ __launch_bounds__(256)
void rotate_pack_qk(const float* __restrict__ t1, const int* __restrict__ mask,
                    const float* __restrict__ rot, ushort* __restrict__ Qb,
                    ushort* __restrict__ Kb)
{
    const int p   = blockIdx.x;
    const int tid = threadIdx.x;
    const int b = p >> 10, s = p & 1023;
    const bool rotated = (mask[p] != 0);   // block-uniform

    __shared__ float R[64][69];
    __shared__ float qv[QKD];
    __shared__ float kv[QKD];

    const float* tq = t1 + (size_t)p * 1024;
    {
        float2 q2 = *(const float2*)(tq + tid*2);
        float2 k2 = *(const float2*)(tq + QKD + tid*2);
        qv[tid*2]   = q2.x; qv[tid*2+1] = q2.y;
        kv[tid*2]   = k2.x; kv[tid*2+1] = k2.y;
        if (rotated) {
            const float* Rg = rot + (size_t)p * 4096;
            const int base = tid * 16;
            const int r = base >> 6, c = base & 63;
            #pragma unroll
            for (int x = 0; x < 16; x += 4) {
                float4 v = *(const float4*)(Rg + base + x);
                R[r][c+x+0] = v.x; R[r][c+x+1] = v.y;
                R[r][c+x+2] = v.z; R[r][c+x+3] = v.w;
            }
        }
    }
    __syncthreads();

    #pragma unroll
    for (int ph = 0; ph < 2; ++ph) {
        const int h = (tid >> 6) + ph*4;
        const int i = tid & 63;
        const float* qh  = &qv[h*64];
        const float* kh2 = &kv[h*64];
        float aq, ak;
        if (rotated) {
            aq = 0.f; ak = 0.f;
            #pragma unroll 8
            for (int j = 0; j < 64; ++j) {
                aq = fmaf(R[i][j], qh[j], aq);    // (R q)_i
                ak = fmaf(R[j][i], kh2[j], ak);   // (R^T k)_i
            }
        } else {
            aq = qh[i]; ak = kh2[i];
        }
        const size_t dst = ((size_t)(b*NH + h)*SEQ + s)*HD + i;
        Qb[dst] = f2bf(aq * SCALE);               // exact pow2 scale
        Kb[dst] = f2bf(ak);
    }
}

// ---------------------------------------------------------------------------
// MFMA Taylor attention, 32x32x16 shapes, P fully in-register.
// Block = (b*8+h, 128 q-rows), 4 waves x 32 q-rows, 1 barrier/iter.
// Swapped QK^T (mfma(K,Q)): lane q = lane&31; cvt_pk + permlane32_swap
// redistribute P into PV A-fragments with zero LDS P traffic.
// ---------------------------------------------------------------------------
__global__ __launch_bounds__(256, 1)
void taylor_attn_mfma(const ushort* __restrict__ Qb, const ushort* __restrict__ Kb,
                      const ushort* __restrict__ Vt, const int* __restrict__ mask,
                      ushort* __restrict__ attn)
{
    const int bh  = blockIdx.x;        // 0..31
    const int qt  = blockIdx.y;        // 0..7 (128 q-rows each)
    const int b   = bh >> 3, h = bh & 7;
    const int tid = threadIdx.x;
    const int lane = tid & 63;
    const int wave = tid >> 6;
    const int l31 = lane & 31;
    const int g   = lane >> 5;         // 0..1

    __shared__ __align__(16) ushort Ks[2][64*64];    // [key][d], src-perm swizzled
    __shared__ __align__(16) ushort Vs[2][128*64];   // [vd][key], src-perm swizzled
    __shared__ float mskAll[SEQ];
    __shared__ float dls[128];

    // stage whole-seq mask once
    {
        int4 mv = *(const int4*)(mask + b*SEQ + tid*4);
        float4 f = make_float4(mv.x ? 1.f : 0.f, mv.y ? 1.f : 0.f,
                               mv.z ? 1.f : 0.f, mv.w ? 1.f : 0.f);
        *(float4*)&mskAll[tid*4] = f;
    }

    // Q fragments (pre-scaled): B-frag q = l31, d = ds*16 + g*8 + j
    const ushort* qrow = Qb + ((size_t)bh*SEQ + qt*128 + wave*32 + l31) * HD + g*8;
    bf16x8 qf[4];
    #pragma unroll
    for (int ds = 0; ds < 4; ++ds) qf[ds] = *(const bf16x8*)(qrow + ds*16);

    // GLD16 per-lane pre-swizzled source pointers (dest linear, read swizzled)
    const int sub  = lane >> 3;                 // row-within-8 == row&7
    const int scol = ((lane & 7) * 8) ^ (sub << 3);
    const ushort* kp0 = Kb + (size_t)bh*SEQ*HD + (size_t)(8*(wave*2+0) + sub)*HD + scol;
    const ushort* kp1 = Kb + (size_t)bh*SEQ*HD + (size_t)(8*(wave*2+1) + sub)*HD + scol;
    const ushort* vp0 = Vt + (size_t)bh*VDD*SEQ + (size_t)(8*(wave*4+0) + sub)*SEQ + scol;
    const ushort* vp1 = Vt + (size_t)bh*VDD*SEQ + (size_t)(8*(wave*4+1) + sub)*SEQ + scol;
    const ushort* vp2 = Vt + (size_t)bh*VDD*SEQ + (size_t)(8*(wave*4+2) + sub)*SEQ + scol;
    const ushort* vp3 = Vt + (size_t)bh*VDD*SEQ + (size_t)(8*(wave*4+3) + sub)*SEQ + scol;

#define ISSUE_TILE(buf, ktn) do {                                          \
    GLD16(kp0 + (size_t)(ktn)*4096, &Ks[buf][(wave*2+0)*512]);             \
    GLD16(kp1 + (size_t)(ktn)*4096, &Ks[buf][(wave*2+1)*512]);             \
    GLD16(vp0 + (size_t)(ktn)*64,   &Vs[buf][(wave*4+0)*512]);             \
    GLD16(vp1 + (size_t)(ktn)*64,   &Vs[buf][(wave*4+1)*512]);             \
    GLD16(vp2 + (size_t)(ktn)*64,   &Vs[buf][(wave*4+2)*512]);             \
    GLD16(vp3 + (size_t)(ktn)*64,   &Vs[buf][(wave*4+3)*512]);             \
} while (0)

    f32x16 acc[4] = {};      // out[32q][vb*32+l31], static-indexed only
    float dacc = 0.f;        // denominator partial for q = l31 (keys of this g)

    ISSUE_TILE(0, 0);

    for (int kt = 0; kt < 16; ++kt) {
        const int cur = kt & 1;
        asm volatile("s_waitcnt vmcnt(0)" ::: "memory");
        __syncthreads();
        if (kt < 15) ISSUE_TILE(cur ^ 1, kt + 1);

        // ---- QK^T swapped: sf{0,1}[reg] = S^T[key][q=l31], 32x32x16 ----
        f32x16 sf0 = {}, sf1 = {};
        __builtin_amdgcn_s_setprio(1);
        #pragma unroll
        for (int ds = 0; ds < 4; ++ds) {
            const int dc = ds*16 + g*8;
            bf16x8 kf0 = *(const bf16x8*)&Ks[cur][SW(l31, dc)];
            bf16x8 kf1 = *(const bf16x8*)&Ks[cur][SW(32 + l31, dc)];
            sf0 = __builtin_amdgcn_mfma_f32_32x32x16_bf16(kf0, qf[ds], sf0, 0, 0, 0);
            sf1 = __builtin_amdgcn_mfma_f32_32x32x16_bf16(kf1, qf[ds], sf1, 0, 0, 0);
        }
        __builtin_amdgcn_s_setprio(0);

        // ---- transform + pack to bf16 words; keys per reg-quad consecutive ----
        // key(reg) = (reg&3) + 8*(reg>>2) + 4g  (within 32-key block)
        const float* mrow = mskAll + kt*64;
        unsigned w0[8], w1[8];
        float dadd = 0.f;
        #pragma unroll
        for (int rr = 0; rr < 4; ++rr) {
            const float4 mqa = *(const float4*)&mrow[8*rr + 4*g];
            const float4 mqb = *(const float4*)&mrow[32 + 8*rr + 4*g];
            float s0 = sf0[rr*4+0], s1 = sf0[rr*4+1];
            float s2 = sf0[rr*4+2], s3 = sf0[rr*4+3];
            float c0 = fmaf(fmaf(0.5f*s0, s0, s0), mqa.x, mqa.x);
            float c1 = fmaf(fmaf(0.5f*s1, s1, s1), mqa.y, mqa.y);
            float c2 = fmaf(fmaf(0.5f*s2, s2, s2), mqa.z, mqa.z);
            float c3 = fmaf(fmaf(0.5f*s3, s3, s3), mqa.w, mqa.w);
            float t0 = sf1[rr*4+0], t1 = sf1[rr*4+1];
            float t2 = sf1[rr*4+2], t3 = sf1[rr*4+3];
            float d0 = fmaf(fmaf(0.5f*t0, t0, t0), mqb.x, mqb.x);
            float d1 = fmaf(fmaf(0.5f*t1, t1, t1), mqb.y, mqb.y);
            float d2 = fmaf(fmaf(0.5f*t2, t2, t2), mqb.z, mqb.z);
            float d3 = fmaf(fmaf(0.5f*t3, t3, t3), mqb.w, mqb.w);
            dadd += ((c0+c1)+(c2+c3)) + ((d0+d1)+(d2+d3));
            w0[rr*2+0] = cvtpk(c0, c1);
            w0[rr*2+1] = cvtpk(c2, c3);
            w1[rr*2+0] = cvtpk(d0, d1);
            w1[rr*2+1] = cvtpk(d2, d3);
        }
        dacc += dadd;
        // redistribute halves: after swap, w[4s..4s+3] is the A-frag for slice s
        plswap(w0[0], w0[2]); plswap(w0[1], w0[3]);
        plswap(w0[4], w0[6]); plswap(w0[5], w0[7]);
        plswap(w1[0], w1[2]); plswap(w1[1], w1[3]);
        plswap(w1[4], w1[6]); plswap(w1[5], w1[7]);

        // ---- PV: out[32q][128vd] += P @ V^T, 32x32x16 ----
        __builtin_amdgcn_s_setprio(1);
        #pragma unroll
        for (int kq = 0; kq < 4; ++kq) {             // global 16-k slice
            union { unsigned u[4]; bf16x8 v; } pu;
            if (kq == 0)      { pu.u[0]=w0[0]; pu.u[1]=w0[1]; pu.u[2]=w0[2]; pu.u[3]=w0[3]; }
            else if (kq == 1) { pu.u[0]=w0[4]; pu.u[1]=w0[5]; pu.u[2]=w0[6]; pu.u[3]=w0[7]; }
            else if (kq == 2) { pu.u[0]=w1[0]; pu.u[1]=w1[1]; pu.u[2]=w1[2]; pu.u[3]=w1[3]; }
            else              { pu.u[0]=w1[4]; pu.u[1]=w1[5]; pu.u[2]=w1[6]; pu.u[3]=w1[7]; }
            const int kcol = kq*16 + g*8;
            acc[0] = __builtin_amdgcn_mfma_f32_32x32x16_bf16(
                pu.v, *(const bf16x8*)&Vs[cur][SW(      l31, kcol)], acc[0], 0, 0, 0);
            acc[1] = __builtin_amdgcn_mfma_f32_32x32x16_bf16(
                pu.v, *(const bf16x8*)&Vs[cur][SW( 32 + l31, kcol)], acc[1], 0, 0, 0);
            acc[2] = __builtin_amdgcn_mfma_f32_32x32x16_bf16(
                pu.v, *(const bf16x8*)&Vs[cur][SW( 64 + l31, kcol)], acc[2], 0, 0, 0);
            acc[3] = __builtin_amdgcn_mfma_f32_32x32x16_bf16(
                pu.v, *(const bf16x8*)&Vs[cur][SW( 96 + l31, kcol)], acc[3], 0, 0, 0);
        }
        __builtin_amdgcn_s_setprio(0);
    }
#undef ISSUE_TILE

    // ---- denominator: combine g halves, distribute via tiny LDS ----
    float dfull = dacc + __shfl_xor(dacc, 32);       // full denom for q=l31
    if (lane < 32) dls[wave*32 + l31] = 1.f / fmaxf(dfull, 1e-6f);
    // wave-local write->read; compiler inserts lgkmcnt
    float inv[16];
    #pragma unroll
    for (int rr = 0; rr < 4; ++rr) {
        float4 iv = *(const float4*)&dls[wave*32 + 8*rr + 4*g];
        inv[rr*4+0] = iv.x; inv[rr*4+1] = iv.y;
        inv[rr*4+2] = iv.z; inv[rr*4+3] = iv.w;
    }

    // D layout 32x32: col = l31 (=vd within block), row q = 4g + 8*(reg>>2) + (reg&3)
    ushort* obase = attn + ((size_t)(b*SEQ + qt*128 + wave*32)) * DIMX + h*VDD + l31;
    #pragma unroll
    for (int vb = 0; vb < 4; ++vb)
        #pragma unroll
        for (int rr = 0; rr < 4; ++rr)
            #pragma unroll
            for (int j = 0; j < 4; ++j) {
                const int q = 4*g + 8*rr + j;
                obase[(size_t)q*DIMX + vb*32] = f2bf(acc[vb][rr*4+j] * inv[rr*4+j]);
            }
}

// ---------------------------------------------------------------------------
extern "C" void kernel_launch(void* const* d_in, const int* in_sizes, int n_in,
                              void* d_out, int out_size, void* d_ws, size_t ws_size,
                              hipStream_t stream)
{
    const float* x    = (const float*)d_in[0];
    const int*   mask = (const int*)d_in[1];
    const float* rot  = (const float*)d_in[2];
    const float* w_t  = (const float*)d_in[3];
    const float* w_o  = (const float*)d_in[4];
    float* out = (float*)d_out;

    // workspace (46 MB):
    // t1 16MB | xbf/attnbf 8MB | wtT 4MB | woT 2MB | Qb 4MB | Kb 4MB | Vt 8MB
    float*  t1     = (float*)d_ws;
    ushort* xbf    = (ushort*)(t1 + (size_t)NPOS * 1024);
    ushort* attnbf = xbf;                            // xbf dead after gemm_qkv
    ushort* wtT    = xbf + (size_t)NPOS * DIMX;
    ushort* woT    = wtT + (size_t)TW * DIMX;
    ushort* Qb     = woT + (size_t)DIMX * DIMX;
    ushort* Kb     = Qb  + (size_t)BATCH * NH * SEQ * HD;
    ushort* Vtp    = Kb  + (size_t)BATCH * NH * SEQ * HD;

    // 0) precision conversions
    cast_bf16<<<(NPOS*DIMX/4 + 255)/256, 256, 0, stream>>>(x, xbf, NPOS*DIMX/4);
    transpose_cast<<<dim3(TW/32, DIMX/32),   256, 0, stream>>>(w_t, wtT, DIMX, TW);
    transpose_cast<<<dim3(DIMX/32, DIMX/32), 256, 0, stream>>>(w_o, woT, DIMX, DIMX);

    // 1) qkv projection: q,k -> t1 fp32; v -> Vt bf16 (transposed per head)
    gemm_qkv<<<dim3(TW/128, NPOS/128), 256, 0, stream>>>(xbf, wtT, t1, Vtp);
    // 2) fused masked rotation + bf16 pack (Q pre-scaled) -> Qb, Kb
    rotate_pack_qk<<<NPOS, 256, 0, stream>>>(t1, mask, rot, Qb, Kb);
    // 3) fused MFMA Taylor attention -> attnbf [NPOS, DIMX] bf16
    taylor_attn_mfma<<<dim3(BATCH*NH, SEQ/128), 256, 0, stream>>>(Qb, Kb, Vtp, mask, attnbf);
    // 4) out = attn @ w_o
    gemm_bf16_mfma<<<dim3(DIMX/128, NPOS/128), 256, 0, stream>>>(attnbf, woT, out, NPOS, DIMX, DIMX);
}

// Round 7
// 110.752 us; speedup vs baseline: 1.0557x; 1.0557x over previous
//
#include <hip/hip_runtime.h>
#include <cstdint>
#include <cstddef>

#define DIMX  1024
#define NH    8
#define HD    64
#define QKD   512            // NH*HD
#define VDD   128            // DIMX/NH
#define BATCH 4
#define SEQ   1024
#define NPOS  (BATCH*SEQ)    // 4096
#define TW    (2*QKD + DIMX) // 2048
#define SCALE 0.125f         // HD^-0.5 (folded into Qb at pack time)

typedef __bf16 bf16x8 __attribute__((ext_vector_type(8)));
typedef float  f32x4  __attribute__((ext_vector_type(4)));
typedef float  f32x16 __attribute__((ext_vector_type(16)));

__device__ __forceinline__ ushort f2bf(float f) {
    unsigned b = __float_as_uint(f);
    return (ushort)((b + 0x7FFFu + ((b >> 16) & 1u)) >> 16);   // RNE, finite data
}

__device__ __forceinline__ unsigned cvtpk(float lo, float hi) {
    unsigned r;
    asm("v_cvt_pk_bf16_f32 %0, %1, %2" : "=v"(r) : "v"(lo), "v"(hi));
    return r;
}

// v_permlane32_swap_b32: a' = [a.lo | b.lo(from lane-32)], b' = [a.hi | b.hi]
__device__ __forceinline__ void plswap(unsigned &a, unsigned &b) {
    asm("v_permlane32_swap_b32 %0, %1" : "+v"(a), "+v"(b));
}

#define GLD16(src, dst) __builtin_amdgcn_global_load_lds(                      \
    (const __attribute__((address_space(1))) unsigned int*)(src),              \
    (__attribute__((address_space(3))) unsigned int*)(dst), 16, 0, 0)

// swizzled LDS element index for [row][col] tiles with 64-elem (128B) rows
#define SW(row, col) ((row)*64 + ((col) ^ (((row)&7)<<3)))

// XCD-aware block swizzle (bijective: nwg % 8 == 0 for all our grids)
__device__ __forceinline__ int2 xcd_swz(int gx, int gy) {
    const int nwg = gx * gy;
    int id = blockIdx.y * gx + blockIdx.x;
    id = (id & 7) * (nwg >> 3) + (id >> 3);
    return make_int2(id % gx, id / gx);
}

// ---------------------------------------------------------------------------
// fp32 -> bf16 cast (same layout). n4 = elem_count/4.
// ---------------------------------------------------------------------------
__global__ __launch_bounds__(256)
void cast_bf16(const float* __restrict__ in, ushort* __restrict__ out, int n4)
{
    const int i = blockIdx.x * 256 + threadIdx.x;
    if (i >= n4) return;
    float4 v = *(const float4*)(in + (size_t)i * 4);
    ushort4 o;
    o.x = f2bf(v.x); o.y = f2bf(v.y); o.z = f2bf(v.z); o.w = f2bf(v.w);
    *(ushort4*)(out + (size_t)i * 4) = o;
}

// ---------------------------------------------------------------------------
// W[K][N] fp32 -> WT[N][K] bf16 (transpose + cast). 32x32 tiles.
// ---------------------------------------------------------------------------
__global__ __launch_bounds__(256)
void transpose_cast(const float* __restrict__ W, ushort* __restrict__ WT,
                    int K, int N)
{
    __shared__ float tile[32][33];
    const int bn = blockIdx.x * 32;
    const int bk = blockIdx.y * 32;
    const int tx = threadIdx.x & 31;
    const int ty = threadIdx.x >> 5;
    #pragma unroll
    for (int i = ty; i < 32; i += 8)
        tile[i][tx] = W[(size_t)(bk + i) * N + bn + tx];
    __syncthreads();
    #pragma unroll
    for (int i = ty; i < 32; i += 8)
        WT[(size_t)(bn + i) * K + bk + tx] = f2bf(tile[tx][i]);
}

// ---------------------------------------------------------------------------
// GEMM1 with split epilogue: cols [0,1024) -> t1 fp32 (q,k);
// cols [1024,2048) -> transposed bf16 Vt[bh][vd][S].
// ---------------------------------------------------------------------------
__global__ __launch_bounds__(256, 2)
void gemm_qkv(const ushort* __restrict__ A, const ushort* __restrict__ BT,
              float* __restrict__ t1, ushort* __restrict__ Vt)
{
    const int K = DIMX, N = TW;
    __shared__ __align__(16) ushort lA[128 * 32];
    __shared__ __align__(16) ushort lB[128 * 32];

    const int2 bij = xcd_swz(N/128, NPOS/128);
    const int tid  = threadIdx.x;
    const int lane = tid & 63;
    const int wave = tid >> 6;
    const int wr   = wave >> 1;
    const int wc   = wave & 1;
    const int bm   = bij.y * 128;
    const int bn   = bij.x * 128;

    const int r0 = wave * 32 + (lane >> 2);
    const int kc = (lane & 3) * 8;
    const ushort* a0 = A  + (size_t)(bm + r0) * K + kc;
    const ushort* a1 = A  + (size_t)(bm + r0 + 16) * K + kc;
    const ushort* b0 = BT + (size_t)(bn + r0) * K + kc;
    const ushort* b1 = BT + (size_t)(bn + r0 + 16) * K + kc;
    ushort* lA0 = lA + wave * 1024;
    ushort* lA1 = lA0 + 512;
    ushort* lB0 = lB + wave * 1024;
    ushort* lB1 = lB0 + 512;

    const int fr = lane & 15;
    const int kh = (lane >> 4) * 8;
    const ushort* ra = lA + (wr * 64 + fr) * 32 + kh;
    const ushort* rb = lB + (wc * 64 + fr) * 32 + kh;

    f32x4 acc[4][4] = {};

    for (int k0 = 0; k0 < K; k0 += 32) {
        GLD16(a0 + k0, lA0);
        GLD16(a1 + k0, lA1);
        GLD16(b0 + k0, lB0);
        GLD16(b1 + k0, lB1);
        asm volatile("s_waitcnt vmcnt(0)" ::: "memory");
        __syncthreads();
        bf16x8 af[4], bfr[4];
        #pragma unroll
        for (int m = 0; m < 4; ++m) af[m]  = *(const bf16x8*)(ra + m * 512);
        #pragma unroll
        for (int n = 0; n < 4; ++n) bfr[n] = *(const bf16x8*)(rb + n * 512);
        #pragma unroll
        for (int m = 0; m < 4; ++m)
            #pragma unroll
            for (int n = 0; n < 4; ++n)
                acc[m][n] = __builtin_amdgcn_mfma_f32_16x16x32_bf16(
                    af[m], bfr[n], acc[m][n], 0, 0, 0);
        __syncthreads();
    }

    const int orow = (lane >> 4) * 4;
    if (bn < 1024) {
        #pragma unroll
        for (int m = 0; m < 4; ++m)
            #pragma unroll
            for (int n = 0; n < 4; ++n) {
                float* dst = t1 + (size_t)(bm + wr * 64 + m * 16 + orow) * 1024
                               + bn + wc * 64 + n * 16 + fr;
                #pragma unroll
                for (int q = 0; q < 4; ++q)
                    dst[(size_t)q * 1024] = acc[m][n][q];
            }
    } else {
        #pragma unroll
        for (int m = 0; m < 4; ++m)
            #pragma unroll
            for (int n = 0; n < 4; ++n) {
                const int row0 = bm + wr * 64 + m * 16 + orow;   // 4-aligned
                const int cv   = bn + wc * 64 + n * 16 + fr - 1024;
                const int hh = cv >> 7, vd = cv & 127;
                const int bb = row0 >> 10, ss = row0 & 1023;
                ushort o4[4];
                #pragma unroll
                for (int q = 0; q < 4; ++q) o4[q] = f2bf(acc[m][n][q]);
                *(ushort4*)&Vt[((size_t)(bb*NH + hh)*VDD + vd)*SEQ + ss] =
                    *(ushort4*)o4;
            }
    }
}

// ---------------------------------------------------------------------------
// GEMM2: C[M][N] fp32 = A[M][K] * BT[N][K]^T (both bf16). + XCD swizzle.
// ---------------------------------------------------------------------------
__global__ __launch_bounds__(256, 2)
void gemm_bf16_mfma(const ushort* __restrict__ A, const ushort* __restrict__ BT,
                    float* __restrict__ C, int M, int N, int K)
{
    __shared__ __align__(16) ushort lA[128 * 32];
    __shared__ __align__(16) ushort lB[128 * 32];

    const int2 bij = xcd_swz(N/128, M/128);
    const int tid  = threadIdx.x;
    const int lane = tid & 63;
    const int wave = tid >> 6;
    const int wr   = wave >> 1;
    const int wc   = wave & 1;
    const int bm   = bij.y * 128;
    const int bn   = bij.x * 128;

    const int r0 = wave * 32 + (lane >> 2);
    const int kc = (lane & 3) * 8;
    const ushort* a0 = A  + (size_t)(bm + r0) * K + kc;
    const ushort* a1 = A  + (size_t)(bm + r0 + 16) * K + kc;
    const ushort* b0 = BT + (size_t)(bn + r0) * K + kc;
    const ushort* b1 = BT + (size_t)(bn + r0 + 16) * K + kc;
    ushort* lA0 = lA + wave * 1024;
    ushort* lA1 = lA0 + 512;
    ushort* lB0 = lB + wave * 1024;
    ushort* lB1 = lB0 + 512;

    const int fr = lane & 15;
    const int kh = (lane >> 4) * 8;
    const ushort* ra = lA + (wr * 64 + fr) * 32 + kh;
    const ushort* rb = lB + (wc * 64 + fr) * 32 + kh;

    f32x4 acc[4][4] = {};

    for (int k0 = 0; k0 < K; k0 += 32) {
        GLD16(a0 + k0, lA0);
        GLD16(a1 + k0, lA1);
        GLD16(b0 + k0, lB0);
        GLD16(b1 + k0, lB1);
        asm volatile("s_waitcnt vmcnt(0)" ::: "memory");
        __syncthreads();
        bf16x8 af[4], bfr[4];
        #pragma unroll
        for (int m = 0; m < 4; ++m) af[m]  = *(const bf16x8*)(ra + m * 512);
        #pragma unroll
        for (int n = 0; n < 4; ++n) bfr[n] = *(const bf16x8*)(rb + n * 512);
        #pragma unroll
        for (int m = 0; m < 4; ++m)
            #pragma unroll
            for (int n = 0; n < 4; ++n)
                acc[m][n] = __builtin_amdgcn_mfma_f32_16x16x32_bf16(
                    af[m], bfr[n], acc[m][n], 0, 0, 0);
        __syncthreads();
    }

    const int orow = (lane >> 4) * 4;
    #pragma unroll
    for (int m = 0; m < 4; ++m)
        #pragma unroll
        for (int n = 0; n < 4; ++n) {
            float* dst = C + (size_t)(bm + wr * 64 + m * 16 + orow) * N
                           + bn + wc * 64 + n * 16 + fr;
            #pragma unroll
            for (int q = 0; q < 4; ++q)
                dst[(size_t)q * N] = acc[m][n][q];
        }
}

// ---------------------------------------------------------------------------
// Fused masked rotation + bf16 pack (SCALE folded into Qb).
// ---------------------------------------------------------------------------
__global__ __launch_bounds__(256)
void rotate_pack_qk(const float* __restrict__ t1, const int* __restrict__ mask,
                    const float* __restrict__ rot, ushort* __restrict__ Qb,
                    ushort* __restrict__ Kb)
{
    const int p   = blockIdx.x;
    const int tid = threadIdx.x;
    const int b = p >> 10, s = p & 1023;
    const bool rotated = (mask[p] != 0);   // block-uniform

    __shared__ float R[64][69];
    __shared__ float qv[QKD];
    __shared__ float kv[QKD];

    const float* tq = t1 + (size_t)p * 1024;
    {
        float2 q2 = *(const float2*)(tq + tid*2);
        float2 k2 = *(const float2*)(tq + QKD + tid*2);
        qv[tid*2]   = q2.x; qv[tid*2+1] = q2.y;
        kv[tid*2]   = k2.x; kv[tid*2+1] = k2.y;
        if (rotated) {
            const float* Rg = rot + (size_t)p * 4096;
            const int base = tid * 16;
            const int r = base >> 6, c = base & 63;
            #pragma unroll
            for (int x = 0; x < 16; x += 4) {
                float4 v = *(const float4*)(Rg + base + x);
                R[r][c+x+0] = v.x; R[r][c+x+1] = v.y;
                R[r][c+x+2] = v.z; R[r][c+x+3] = v.w;
            }
        }
    }
    __syncthreads();

    #pragma unroll
    for (int ph = 0; ph < 2; ++ph) {
        const int h = (tid >> 6) + ph*4;
        const int i = tid & 63;
        const float* qh  = &qv[h*64];
        const float* kh2 = &kv[h*64];
        float aq, ak;
        if (rotated) {
            aq = 0.f; ak = 0.f;
            #pragma unroll 8
            for (int j = 0; j < 64; ++j) {
                aq = fmaf(R[i][j], qh[j], aq);    // (R q)_i
                ak = fmaf(R[j][i], kh2[j], ak);   // (R^T k)_i
            }
        } else {
            aq = qh[i]; ak = kh2[i];
        }
        const size_t dst = ((size_t)(b*NH + h)*SEQ + s)*HD + i;
        Qb[dst] = f2bf(aq * SCALE);               // exact pow2 scale
        Kb[dst] = f2bf(ak);
    }
}

// ---------------------------------------------------------------------------
// MFMA Taylor attention, 32x32x16, in-register P, SPLIT-K across wave pairs.
// Block = (bh, 64 q-rows), 4 waves: wave = kh*2+qg; qg = 32-q group,
// kh = key-half (kt 0-7 / 8-15). Grid 512 -> 2048 waves = 2/SIMD.
// K double-buffered per pair (hidden); V single-buffered (lands under QK).
// Epilogue: kh1 writes partial O/denom to LDS; kh0 combines and stores.
// ---------------------------------------------------------------------------
__global__ __launch_bounds__(256, 2)
void taylor_attn_mfma(const ushort* __restrict__ Qb, const ushort* __restrict__ Kb,
                      const ushort* __restrict__ Vt, const int* __restrict__ mask,
                      ushort* __restrict__ attn)
{
    const int bh  = blockIdx.x;        // 0..31
    const int qt  = blockIdx.y;        // 0..15 (64 q-rows each)
    const int b   = bh >> 3, h = bh & 7;
    const int tid = threadIdx.x;
    const int lane = tid & 63;
    const int wave = tid >> 6;
    const int kh  = wave >> 1;         // key-half
    const int qg  = wave & 1;          // q-group (32 rows)
    const int l31 = lane & 31;
    const int g   = lane >> 5;         // 0..1

    // 64KB shared tile arena: [kh0 Kdbuf 16K][kh1 Kdbuf 16K][kh0 V 16K][kh1 V 16K]
    __shared__ __align__(16) ushort smem[32768];
    __shared__ float mskAll[SEQ];
    __shared__ float dpart[64];
    __shared__ float dinv2[64];

    ushort* Ksp = smem + kh * 8192;            // my pair's K dbuf [2][4096]
    ushort* Vsp = smem + 16384 + kh * 8192;    // my pair's V [8192]
    float*  comb = (float*)smem;               // epilogue partial-O (32KB)

    // stage whole-seq mask once
    {
        int4 mv = *(const int4*)(mask + b*SEQ + tid*4);
        float4 f = make_float4(mv.x ? 1.f : 0.f, mv.y ? 1.f : 0.f,
                               mv.z ? 1.f : 0.f, mv.w ? 1.f : 0.f);
        *(float4*)&mskAll[tid*4] = f;
    }

    // Q fragments (pre-scaled): B-frag q = l31, d = ds*16 + g*8 + j
    const ushort* qrow = Qb + ((size_t)bh*SEQ + qt*64 + qg*32 + l31) * HD + g*8;
    bf16x8 qf[4];
    #pragma unroll
    for (int ds = 0; ds < 4; ++ds) qf[ds] = *(const bf16x8*)(qrow + ds*16);

    // GLD16 per-lane pre-swizzled source (dest linear, read swizzled)
    const int sub  = lane >> 3;                 // row-within-8 == row&7
    const int scol = ((lane & 7) * 8) ^ (sub << 3);
    const ushort* Kbase = Kb + (size_t)bh*SEQ*HD;
    const ushort* Vbase = Vt + (size_t)bh*VDD*SEQ;

#define ISSUE_K(buf, ktn) do {                                                 \
    _Pragma("unroll")                                                          \
    for (int i_ = 0; i_ < 4; ++i_)                                             \
        GLD16(Kbase + ((size_t)(ktn)*64 + 8*(qg*4+i_) + sub)*HD + scol,        \
              Ksp + (buf)*4096 + (qg*4+i_)*512);                               \
} while (0)
#define ISSUE_V(ktn) do {                                                      \
    _Pragma("unroll")                                                          \
    for (int i_ = 0; i_ < 8; ++i_)                                             \
        GLD16(Vbase + (size_t)(8*(qg*8+i_) + sub)*SEQ + (ktn)*64 + scol,       \
              Vsp + (qg*8+i_)*512);                                            \
} while (0)

    f32x16 acc[4] = {};      // out[32q][vb*32+l31]
    float dacc = 0.f;        // denominator partial (q = l31, my keys, my g-half)

    // prologue: K(first) into buf 0
    ISSUE_K(0, kh*8);
    asm volatile("s_waitcnt vmcnt(0)" ::: "memory");
    __syncthreads();

    for (int it = 0; it < 8; ++it) {
        const int kt = kh*8 + it;
        const int cb = it & 1;
        // stage V(it) (Vsp safe: prev-iter end barrier) and K(it+1)
        ISSUE_V(kt);
        if (it < 7) ISSUE_K(cb ^ 1, kt + 1);

        // ---- QK^T swapped from resident K buffer (no wait) ----
        f32x16 sf0 = {}, sf1 = {};
        __builtin_amdgcn_s_setprio(1);
        #pragma unroll
        for (int ds = 0; ds < 4; ++ds) {
            const int dc = ds*16 + g*8;
            bf16x8 kf0 = *(const bf16x8*)&Ksp[cb*4096 + SW(l31, dc)];
            bf16x8 kf1 = *(const bf16x8*)&Ksp[cb*4096 + SW(32 + l31, dc)];
            sf0 = __builtin_amdgcn_mfma_f32_32x32x16_bf16(kf0, qf[ds], sf0, 0, 0, 0);
            sf1 = __builtin_amdgcn_mfma_f32_32x32x16_bf16(kf1, qf[ds], sf1, 0, 0, 0);
        }
        __builtin_amdgcn_s_setprio(0);

        // ---- transform + pack (keys per reg-quad consecutive) ----
        const float* mrow = mskAll + kt*64;
        unsigned w0[8], w1[8];
        float dadd = 0.f;
        #pragma unroll
        for (int rr = 0; rr < 4; ++rr) {
            const float4 mqa = *(const float4*)&mrow[8*rr + 4*g];
            const float4 mqb = *(const float4*)&mrow[32 + 8*rr + 4*g];
            float s0 = sf0[rr*4+0], s1 = sf0[rr*4+1];
            float s2 = sf0[rr*4+2], s3 = sf0[rr*4+3];
            float c0 = fmaf(fmaf(0.5f*s0, s0, s0), mqa.x, mqa.x);
            float c1 = fmaf(fmaf(0.5f*s1, s1, s1), mqa.y, mqa.y);
            float c2 = fmaf(fmaf(0.5f*s2, s2, s2), mqa.z, mqa.z);
            float c3 = fmaf(fmaf(0.5f*s3, s3, s3), mqa.w, mqa.w);
            float t0 = sf1[rr*4+0], t1 = sf1[rr*4+1];
            float t2 = sf1[rr*4+2], t3 = sf1[rr*4+3];
            float d0 = fmaf(fmaf(0.5f*t0, t0, t0), mqb.x, mqb.x);
            float d1 = fmaf(fmaf(0.5f*t1, t1, t1), mqb.y, mqb.y);
            float d2 = fmaf(fmaf(0.5f*t2, t2, t2), mqb.z, mqb.z);
            float d3 = fmaf(fmaf(0.5f*t3, t3, t3), mqb.w, mqb.w);
            dadd += ((c0+c1)+(c2+c3)) + ((d0+d1)+(d2+d3));
            w0[rr*2+0] = cvtpk(c0, c1);
            w0[rr*2+1] = cvtpk(c2, c3);
            w1[rr*2+0] = cvtpk(d0, d1);
            w1[rr*2+1] = cvtpk(d2, d3);
        }
        dacc += dadd;
        plswap(w0[0], w0[2]); plswap(w0[1], w0[3]);
        plswap(w0[4], w0[6]); plswap(w0[5], w0[7]);
        plswap(w1[0], w1[2]); plswap(w1[1], w1[3]);
        plswap(w1[4], w1[6]); plswap(w1[5], w1[7]);

        // ---- V (and next K) landed; make visible to both pair waves ----
        asm volatile("s_waitcnt vmcnt(0)" ::: "memory");
        __syncthreads();

        // ---- PV: out[32q][128vd] += P @ V^T ----
        __builtin_amdgcn_s_setprio(1);
        #pragma unroll
        for (int kq = 0; kq < 4; ++kq) {
            union { unsigned u[4]; bf16x8 v; } pu;
            if (kq == 0)      { pu.u[0]=w0[0]; pu.u[1]=w0[1]; pu.u[2]=w0[2]; pu.u[3]=w0[3]; }
            else if (kq == 1) { pu.u[0]=w0[4]; pu.u[1]=w0[5]; pu.u[2]=w0[6]; pu.u[3]=w0[7]; }
            else if (kq == 2) { pu.u[0]=w1[0]; pu.u[1]=w1[1]; pu.u[2]=w1[2]; pu.u[3]=w1[3]; }
            else              { pu.u[0]=w1[4]; pu.u[1]=w1[5]; pu.u[2]=w1[6]; pu.u[3]=w1[7]; }
            const int kcol = kq*16 + g*8;
            acc[0] = __builtin_amdgcn_mfma_f32_32x32x16_bf16(
                pu.v, *(const bf16x8*)&Vsp[SW(      l31, kcol)], acc[0], 0, 0, 0);
            acc[1] = __builtin_amdgcn_mfma_f32_32x32x16_bf16(
                pu.v, *(const bf16x8*)&Vsp[SW( 32 + l31, kcol)], acc[1], 0, 0, 0);
            acc[2] = __builtin_amdgcn_mfma_f32_32x32x16_bf16(
                pu.v, *(const bf16x8*)&Vsp[SW( 64 + l31, kcol)], acc[2], 0, 0, 0);
            acc[3] = __builtin_amdgcn_mfma_f32_32x32x16_bf16(
                pu.v, *(const bf16x8*)&Vsp[SW( 96 + l31, kcol)], acc[3], 0, 0, 0);
        }
        __builtin_amdgcn_s_setprio(0);
        __syncthreads();   // all reads of Vsp / Ksp[cb] done before overwrite
    }
#undef ISSUE_K
#undef ISSUE_V

    // ---- combine key-halves ----
    // full denom over my wave's 512 keys (both g halves hold it for q=l31)
    const float dhalf = dacc + __shfl_xor(dacc, 32);

    if (kh == 1) {
        float* cbp = comb + qg * 4096;                 // [vd 128][q 32] f32
        #pragma unroll
        for (int vb = 0; vb < 4; ++vb)
            #pragma unroll
            for (int rr = 0; rr < 4; ++rr) {
                float4 v = make_float4(acc[vb][rr*4+0], acc[vb][rr*4+1],
                                       acc[vb][rr*4+2], acc[vb][rr*4+3]);
                *(float4*)&cbp[(vb*32 + l31)*32 + 4*g + 8*rr] = v;
            }
        if (lane < 32) dpart[qg*32 + l31] = dhalf;
    }
    __syncthreads();
    if (kh == 0) {
        float* cbp = comb + qg * 4096;
        const float dtot = dhalf + dpart[qg*32 + l31];
        if (lane < 32) dinv2[qg*32 + l31] = 1.f / fmaxf(dtot, 1e-6f);
        #pragma unroll
        for (int vb = 0; vb < 4; ++vb)
            #pragma unroll
            for (int rr = 0; rr < 4; ++rr) {
                float4 v = *(const float4*)&cbp[(vb*32 + l31)*32 + 4*g + 8*rr];
                acc[vb][rr*4+0] += v.x; acc[vb][rr*4+1] += v.y;
                acc[vb][rr*4+2] += v.z; acc[vb][rr*4+3] += v.w;
            }
        float inv[16];
        #pragma unroll
        for (int rr = 0; rr < 4; ++rr) {
            float4 iv = *(const float4*)&dinv2[qg*32 + 8*rr + 4*g];
            inv[rr*4+0] = iv.x; inv[rr*4+1] = iv.y;
            inv[rr*4+2] = iv.z; inv[rr*4+3] = iv.w;
        }
        ushort* obase = attn + ((size_t)(b*SEQ + qt*64 + qg*32)) * DIMX
                      + h*VDD + l31;
        #pragma unroll
        for (int vb = 0; vb < 4; ++vb)
            #pragma unroll
            for (int rr = 0; rr < 4; ++rr)
                #pragma unroll
                for (int j = 0; j < 4; ++j) {
                    const int q = 4*g + 8*rr + j;
                    obase[(size_t)q*DIMX + vb*32] = f2bf(acc[vb][rr*4+j] * inv[rr*4+j]);
                }
    }
}

// ---------------------------------------------------------------------------
extern "C" void kernel_launch(void* const* d_in, const int* in_sizes, int n_in,
                              void* d_out, int out_size, void* d_ws, size_t ws_size,
                              hipStream_t stream)
{
    const float* x    = (const float*)d_in[0];
    const int*   mask = (const int*)d_in[1];
    const float* rot  = (const float*)d_in[2];
    const float* w_t  = (const float*)d_in[3];
    const float* w_o  = (const float*)d_in[4];
    float* out = (float*)d_out;

    // workspace (46 MB):
    // t1 16MB | xbf/attnbf 8MB | wtT 4MB | woT 2MB | Qb 4MB | Kb 4MB | Vt 8MB
    float*  t1     = (float*)d_ws;
    ushort* xbf    = (ushort*)(t1 + (size_t)NPOS * 1024);
    ushort* attnbf = xbf;                            // xbf dead after gemm_qkv
    ushort* wtT    = xbf + (size_t)NPOS * DIMX;
    ushort* woT    = wtT + (size_t)TW * DIMX;
    ushort* Qb     = woT + (size_t)DIMX * DIMX;
    ushort* Kb     = Qb  + (size_t)BATCH * NH * SEQ * HD;
    ushort* Vtp    = Kb  + (size_t)BATCH * NH * SEQ * HD;

    // 0) precision conversions
    cast_bf16<<<(NPOS*DIMX/4 + 255)/256, 256, 0, stream>>>(x, xbf, NPOS*DIMX/4);
    transpose_cast<<<dim3(TW/32, DIMX/32),   256, 0, stream>>>(w_t, wtT, DIMX, TW);
    transpose_cast<<<dim3(DIMX/32, DIMX/32), 256, 0, stream>>>(w_o, woT, DIMX, DIMX);

    // 1) qkv projection: q,k -> t1 fp32; v -> Vt bf16 (transposed per head)
    gemm_qkv<<<dim3(TW/128, NPOS/128), 256, 0, stream>>>(xbf, wtT, t1, Vtp);
    // 2) fused masked rotation + bf16 pack (Q pre-scaled) -> Qb, Kb
    rotate_pack_qk<<<NPOS, 256, 0, stream>>>(t1, mask, rot, Qb, Kb);
    // 3) fused MFMA Taylor attention (split-K) -> attnbf [NPOS, DIMX] bf16
    taylor_attn_mfma<<<dim3(BATCH*NH, SEQ/64), 256, 0, stream>>>(Qb, Kb, Vtp, mask, attnbf);
    // 4) out = attn @ w_o
    gemm_bf16_mfma<<<dim3(DIMX/128, NPOS/128), 256, 0, stream>>>(attnbf, woT, out, NPOS, DIMX, DIMX);
}